// Round 4
// baseline (277.001 us; speedup 1.0000x reference)
//
#include <hip/hip_runtime.h>
#include <cstdint>

#define B_  8
#define S_  2048
#define E_  1024
#define H_  128
#define NC_ 16          // chunks per sequence (S_/128)

typedef __attribute__((ext_vector_type(8))) short bf16x8;
typedef __attribute__((ext_vector_type(4))) float f32x4;

__device__ __forceinline__ short f2bf(float f){
  uint32_t u = __builtin_bit_cast(uint32_t, f);
  u = (u + 0x7fffu + ((u >> 16) & 1u)) >> 16;   // RNE
  return (short)u;
}
__device__ __forceinline__ float bf2f(short s){
  uint32_t u = ((uint32_t)(uint16_t)s) << 16;
  return __builtin_bit_cast(float, u);
}

// ---------------------------------------------------------------------------
// Kernel 1: W (E,H) f32 -> Wt (H,E) bf16, LDS-tiled transpose
// ---------------------------------------------------------------------------
__global__ __launch_bounds__(256) void wt_kernel(
    const float* __restrict__ WQ, const float* __restrict__ WK,
    const float* __restrict__ WV,
    short* __restrict__ WtQ, short* __restrict__ WtK, short* __restrict__ WtV)
{
  int which = blockIdx.z;
  const float* W = which == 0 ? WQ : which == 1 ? WK : WV;
  short* Wt      = which == 0 ? WtQ : which == 1 ? WtK : WtV;
  int k0 = blockIdx.x * 32, n0 = blockIdx.y * 32;
  __shared__ float t[32][33];
  int tx = threadIdx.x & 31, ty = threadIdx.x >> 5;
  #pragma unroll
  for (int i = 0; i < 4; i++)
    t[ty + i * 8][tx] = W[(size_t)(k0 + ty + i * 8) * H_ + n0 + tx];
  __syncthreads();
  #pragma unroll
  for (int i = 0; i < 4; i++)
    Wt[(size_t)(n0 + ty + i * 8) * E_ + k0 + tx] = f2bf(t[tx][ty + i * 8]);
}

// ---------------------------------------------------------------------------
// Kernel 2: projections — r0 VERBATIM (best measured: 82.5 µs).
// 64-row blocks (grid 256x3), 34.8KB LDS -> 4 blocks/CU-capable. K in 8
// chunks of 128; inside a chunk the 4 k-steps are barrier-free (B resident
// in padded LDS, A in regs). One combined vm drain per chunk.
// r1 (64-k dbuf pipeline), r2 (no-LDS direct B), r3 (A through LDS) all
// regressed — this structure is a verified local optimum; do not touch.
// ---------------------------------------------------------------------------
__global__ __launch_bounds__(256) void proj_kernel(
    const float* __restrict__ Xq, const float* __restrict__ Xk,
    const float* __restrict__ Xv,
    const short* __restrict__ Wtq, const short* __restrict__ Wtk,
    const short* __restrict__ Wtv,
    short* __restrict__ q, short* __restrict__ k,
    short* __restrict__ kT, short* __restrict__ vT)
{
  int which = blockIdx.y;
  const float* X  = which == 0 ? Xq  : which == 1 ? Xk  : Xv;
  const short* Wt = which == 0 ? Wtq : which == 1 ? Wtk : Wtv;

  int tid = threadIdx.x, lane = tid & 63, wave = tid >> 6;
  int lr = lane & 15, lq = lane >> 4;
  int rowbase = blockIdx.x * 64 + wave * 16;   // wave's 16 rows

  __shared__ short Bs[128 * 136];              // padded stride 136 (34.8 KB)

  const float* xr = X + (size_t)(rowbase + lr) * E_ + lq * 8;

  f32x4 acc[8];
  #pragma unroll
  for (int tn = 0; tn < 8; tn++) acc[tn] = (f32x4){0.f, 0.f, 0.f, 0.f};

  for (int kc = 0; kc < 8; kc++){              // 128-k chunks
    if (kc) __syncthreads();                   // prev chunk's reads done
    // volley: stage B chunk, 128 rows x 128 shorts; 8 x 16B per thread
    #pragma unroll
    for (int v = 0; v < 8; v++){
      int c = v * 256 + tid;
      int n = c >> 4, off = (c & 15) * 8;
      *(bf16x8*)(&Bs[n * 136 + off]) =
          *(const bf16x8*)(Wt + (size_t)n * E_ + kc * 128 + off);
    }
    // A for the whole chunk: 8 x f32x4 in flight
    f32x4 ar[8];
    #pragma unroll
    for (int s = 0; s < 4; s++){
      ar[2 * s]     = *(const f32x4*)(xr + kc * 128 + s * 32);
      ar[2 * s + 1] = *(const f32x4*)(xr + kc * 128 + s * 32 + 4);
    }
    __syncthreads();                           // single drain per chunk
    #pragma unroll
    for (int s = 0; s < 4; s++){
      bf16x8 a;
      #pragma unroll
      for (int j = 0; j < 4; j++){
        a[j] = f2bf(ar[2 * s][j]); a[4 + j] = f2bf(ar[2 * s + 1][j]);
      }
      #pragma unroll
      for (int tn = 0; tn < 8; tn++){
        bf16x8 bfr = *(const bf16x8*)(&Bs[(tn * 16 + lr) * 136 + s * 32 + lq * 8]);
        acc[tn] = __builtin_amdgcn_mfma_f32_16x16x32_bf16(a, bfr, acc[tn], 0, 0, 0);
      }
    }
  }

  // ---- epilogue: C/D layout col=lane&15, row=(lane>>4)*4+reg ----
  if (which <= 1){
    short* P = which == 0 ? q : k;
    #pragma unroll
    for (int tn = 0; tn < 8; tn++)
      #pragma unroll
      for (int r4 = 0; r4 < 4; r4++)
        P[(size_t)(rowbase + lq * 4 + r4) * H_ + tn * 16 + lr] = f2bf(acc[tn][r4]);
  }
  if (which >= 1){
    short* T = which == 1 ? kT : vT;
    int b = rowbase >> 11, srow = rowbase & 2047;
    #pragma unroll
    for (int tn = 0; tn < 8; tn++){
      union { short sh[4]; uint2 u; } pk;
      #pragma unroll
      for (int r4 = 0; r4 < 4; r4++) pk.sh[r4] = f2bf(acc[tn][r4]);
      *(uint2*)(T + ((size_t)b * H_ + tn * 16 + lr) * S_ + srow + lq * 4) = pk.u;
    }
  }
}

// ---------------------------------------------------------------------------
// Kernel 3: per-chunk state M_j[h'][h] = sum_t V[t][h'] K[t][h].
// Col QUARTERS (32 h each) -> grid (15,4,B) = 480 blocks, 2 blocks/CU.
// j=15 dropped (exclusive prefix never uses M_15). One barrier.
// ---------------------------------------------------------------------------
__global__ __launch_bounds__(256) void chunk_state(
    const short* __restrict__ vT, const short* __restrict__ kT,
    float* __restrict__ M)
{
  int j = blockIdx.x, qtr = blockIdx.y, b = blockIdx.z;
  int tid = threadIdx.x, lane = tid & 63, wave = tid >> 6;
  int wrow = wave * 32;
  int lr = lane & 15, lq = lane >> 4;

  __shared__ short As[128 * 136];   // vT rows (h' x t), 34.8 KB
  __shared__ short Bs[32 * 136];    // kT quarter rows (h x t), 8.7 KB

  const short* vtb = vT + (size_t)b * H_ * S_ + j * 128;
  const short* ktb = kT + (size_t)b * H_ * S_ + (size_t)qtr * 32 * S_ + j * 128;

  #pragma unroll
  for (int v = 0; v < 8; v++){
    int c = v * 256 + tid;
    int r = c >> 4, off = (c & 15) * 8;
    *(bf16x8*)(&As[r * 136 + off]) = *(const bf16x8*)(vtb + (size_t)r * S_ + off);
  }
  #pragma unroll
  for (int v = 0; v < 2; v++){
    int c = v * 256 + tid;
    int r = c >> 4, off = (c & 15) * 8;
    *(bf16x8*)(&Bs[r * 136 + off]) = *(const bf16x8*)(ktb + (size_t)r * S_ + off);
  }
  __syncthreads();

  f32x4 acc[2][2];
  #pragma unroll
  for (int a = 0; a < 2; a++)
    #pragma unroll
    for (int c = 0; c < 2; c++) acc[a][c] = (f32x4){0.f, 0.f, 0.f, 0.f};

  #pragma unroll
  for (int s = 0; s < 4; s++){
    int t0 = s * 32;
    bf16x8 af[2], bf[2];
    #pragma unroll
    for (int tm = 0; tm < 2; tm++)
      af[tm] = *(const bf16x8*)(&As[(wrow + tm * 16 + lr) * 136 + t0 + lq * 8]);
    #pragma unroll
    for (int tn = 0; tn < 2; tn++)
      bf[tn] = *(const bf16x8*)(&Bs[(tn * 16 + lr) * 136 + t0 + lq * 8]);
    #pragma unroll
    for (int tm = 0; tm < 2; tm++)
      #pragma unroll
      for (int tn = 0; tn < 2; tn++)
        acc[tm][tn] = __builtin_amdgcn_mfma_f32_16x16x32_bf16(
            af[tm], bf[tn], acc[tm][tn], 0, 0, 0);
  }

  float* mb = M + (size_t)(b * NC_ + j) * 16384;
  #pragma unroll
  for (int tm = 0; tm < 2; tm++)
    #pragma unroll
    for (int tn = 0; tn < 2; tn++)
      #pragma unroll
      for (int r4 = 0; r4 < 4; r4++){
        int row = wrow + tm * 16 + lq * 4 + r4;
        int col = qtr * 32 + tn * 16 + lr;
        mb[row * 128 + col] = acc[tm][tn][r4];
      }
}

// ---------------------------------------------------------------------------
// Kernel 4 (was 5) v5: per (b, chunk i, row-QUARTER): 32 rows of
//   O = (Q_i K_i^T . tril) V_i + Q_i * (sum_{j<i} M_j)
// FUSED PREFIX: each block computes its own exclusive state sum from M
// (f32, L2-resident, barrier-free f32x4 accumulate; thread owns 64 elems),
// hi/lo-splits it into the K/V LDS buffers after their readers are done.
// Removes prefix_state kernel + Shi/Slo HBM round-trip + one launch gap.
// Same verified MFMA fragment layouts and 4-barrier skeleton as before;
// i==0 skips the state phases entirely (block-uniform branch).
// ---------------------------------------------------------------------------
__global__ __launch_bounds__(256) void passC(
    const short* __restrict__ qb, const short* __restrict__ kb,
    const short* __restrict__ vT, const float* __restrict__ M,
    float* __restrict__ out)
{
  int i = blockIdx.x, qtr = blockIdx.y, b = blockIdx.z;
  int roff = qtr * 32;
  int tid = threadIdx.x, lane = tid & 63, wave = tid >> 6;
  int wcol = wave * 32;
  int lr = lane & 15, lq = lane >> 4;

  __shared__ short Ss[32 * 136];    // masked scores (8.7 KB)
  __shared__ short Bt0[128 * 136];  // K, then State_hi  (34.8 KB)
  __shared__ short Bt1[128 * 136];  // V, then State_lo  (34.8 KB)

  const short* qbase = qb + ((size_t)b * S_ + i * 128 + roff) * H_;
  const short* kbase = kb + ((size_t)b * S_ + i * 128) * H_;
  const short* vtb   = vT + (size_t)b * H_ * S_ + i * 128;
  const float* mbase = M + (size_t)b * NC_ * 16384;

  // ---- entry: K,V volleys + Q frags to regs ----
  bf16x8 kst[8], vst[8];
  #pragma unroll
  for (int v = 0; v < 8; v++){
    int c = v * 256 + tid;
    int r = c >> 4, off = (c & 15) * 8;
    kst[v] = *(const bf16x8*)(kbase + (size_t)r * H_ + off);
    vst[v] = *(const bf16x8*)(vtb  + (size_t)r * S_ + off);
  }
  bf16x8 aq[2][4];   // Q rows tm*16+lr (32 rows of this quarter)
  #pragma unroll
  for (int tm = 0; tm < 2; tm++)
    #pragma unroll
    for (int hs = 0; hs < 4; hs++)
      aq[tm][hs] = *(const bf16x8*)(
          qbase + (size_t)(tm * 16 + lr) * H_ + hs * 32 + lq * 8);

  // K -> Bt0
  #pragma unroll
  for (int v = 0; v < 8; v++){
    int c = v * 256 + tid;
    int r = c >> 4, off = (c & 15) * 8;
    *(bf16x8*)(&Bt0[r * 136 + off]) = kst[v];
  }
  __syncthreads();                           // barrier 1

  f32x4 accS[2][2];
  #pragma unroll
  for (int a = 0; a < 2; a++)
    #pragma unroll
    for (int c = 0; c < 2; c++) accS[a][c] = (f32x4){0.f, 0.f, 0.f, 0.f};

  // ---- phase 1: S = Q K^T, wave's t-slice = wcol..wcol+31 ----
  #pragma unroll
  for (int hs = 0; hs < 4; hs++){
    bf16x8 bf[2];
    #pragma unroll
    for (int tn = 0; tn < 2; tn++)
      bf[tn] = *(const bf16x8*)(&Bt0[(wcol + tn * 16 + lr) * 136 + hs * 32 + lq * 8]);
    #pragma unroll
    for (int tm = 0; tm < 2; tm++)
      #pragma unroll
      for (int tn = 0; tn < 2; tn++)
        accS[tm][tn] = __builtin_amdgcn_mfma_f32_16x16x32_bf16(
            aq[tm][hs], bf[tn], accS[tm][tn], 0, 0, 0);
  }

  // ---- fused exclusive prefix: msum = sum_{j<i} M_j, thread owns
  // State row mr = tid>>1 (h'), cols mc0..mc0+63 (h); 16 f32x4, no barriers.
  int mr = tid >> 1, mc0 = (tid & 1) * 64;
  f32x4 msum[16];
  #pragma unroll
  for (int qd = 0; qd < 16; qd++) msum[qd] = (f32x4){0.f, 0.f, 0.f, 0.f};
  for (int j = 0; j < i; j++){
    const float* mj = mbase + (size_t)j * 16384 + (size_t)mr * 128 + mc0;
    #pragma unroll
    for (int qd = 0; qd < 16; qd++)
      msum[qd] += *(const f32x4*)(mj + qd * 4);
  }

  // ---- phase 2: mask + bf16 -> Ss; land V -> Bt1 ----
  #pragma unroll
  for (int tm = 0; tm < 2; tm++)
    #pragma unroll
    for (int tn = 0; tn < 2; tn++)
      #pragma unroll
      for (int r4 = 0; r4 < 4; r4++){
        int row = tm * 16 + lq * 4 + r4;            // local row 0..31
        int col = wcol + tn * 16 + lr;              // t index 0..127
        float vv = (col <= roff + row) ? accS[tm][tn][r4] : 0.f;
        Ss[row * 136 + col] = f2bf(vv);
      }
  #pragma unroll
  for (int v = 0; v < 8; v++){
    int c = v * 256 + tid;
    int r = c >> 4, off = (c & 15) * 8;
    *(bf16x8*)(&Bt1[r * 136 + off]) = vst[v];
  }
  f32x4 acc[2][2];
  #pragma unroll
  for (int a = 0; a < 2; a++)
    #pragma unroll
    for (int c = 0; c < 2; c++) acc[a][c] = (f32x4){0.f, 0.f, 0.f, 0.f};
  __syncthreads();                           // barrier 2

  // ---- phase 3a: O += S V, wave's h'-slice = wcol ----
  #pragma unroll
  for (int s = 0; s < 4; s++){
    int t0 = s * 32;
    bf16x8 af[2], bf[2];
    #pragma unroll
    for (int tm = 0; tm < 2; tm++)
      af[tm] = *(const bf16x8*)(&Ss[(tm * 16 + lr) * 136 + t0 + lq * 8]);
    #pragma unroll
    for (int tn = 0; tn < 2; tn++)
      bf[tn] = *(const bf16x8*)(&Bt1[(wcol + tn * 16 + lr) * 136 + t0 + lq * 8]);
    #pragma unroll
    for (int tm = 0; tm < 2; tm++)
      #pragma unroll
      for (int tn = 0; tn < 2; tn++)
        acc[tm][tn] = __builtin_amdgcn_mfma_f32_16x16x32_bf16(
            af[tm], bf[tn], acc[tm][tn], 0, 0, 0);
  }

  if (i > 0){
    // State_hi -> Bt0 (Bt0 readers done since barrier 2)
    #pragma unroll
    for (int qd = 0; qd < 16; qd++){
      union { short s[4]; uint2 u; } ph;
      #pragma unroll
      for (int e = 0; e < 4; e++) ph.s[e] = f2bf(msum[qd][e]);
      *(uint2*)(&Bt0[mr * 136 + mc0 + qd * 4]) = ph.u;
    }
    __syncthreads();                         // barrier 3

    // ---- phase 3b-hi: O += Q * State_hi (Bt0); land State_lo -> Bt1 ----
    #pragma unroll
    for (int hs = 0; hs < 4; hs++){
      bf16x8 bf[2];
      #pragma unroll
      for (int tn = 0; tn < 2; tn++)
        bf[tn] = *(const bf16x8*)(&Bt0[(wcol + tn * 16 + lr) * 136 + hs * 32 + lq * 8]);
      #pragma unroll
      for (int tm = 0; tm < 2; tm++)
        #pragma unroll
        for (int tn = 0; tn < 2; tn++)
          acc[tm][tn] = __builtin_amdgcn_mfma_f32_16x16x32_bf16(
              aq[tm][hs], bf[tn], acc[tm][tn], 0, 0, 0);
    }
    #pragma unroll
    for (int qd = 0; qd < 16; qd++){
      union { short s[4]; uint2 u; } pl;
      #pragma unroll
      for (int e = 0; e < 4; e++){
        short h = f2bf(msum[qd][e]);
        pl.s[e] = f2bf(msum[qd][e] - bf2f(h));
      }
      *(uint2*)(&Bt1[mr * 136 + mc0 + qd * 4]) = pl.u;
    }
    __syncthreads();                         // barrier 4

    // ---- phase 3b-lo: O += Q * State_lo (Bt1) ----
    #pragma unroll
    for (int hs = 0; hs < 4; hs++){
      bf16x8 bf[2];
      #pragma unroll
      for (int tn = 0; tn < 2; tn++)
        bf[tn] = *(const bf16x8*)(&Bt1[(wcol + tn * 16 + lr) * 136 + hs * 32 + lq * 8]);
      #pragma unroll
      for (int tm = 0; tm < 2; tm++)
        #pragma unroll
        for (int tn = 0; tn < 2; tn++)
          acc[tm][tn] = __builtin_amdgcn_mfma_f32_16x16x32_bf16(
              aq[tm][hs], bf[tn], acc[tm][tn], 0, 0, 0);
    }
  }

  // ---- epilogue ----
  float* ob = out + ((size_t)b * S_ + i * 128 + roff) * H_;
  #pragma unroll
  for (int tm = 0; tm < 2; tm++)
    #pragma unroll
    for (int tn = 0; tn < 2; tn++)
      #pragma unroll
      for (int r4 = 0; r4 < 4; r4++){
        int row = tm * 16 + lq * 4 + r4;
        int col = wcol + tn * 16 + lr;
        ob[(size_t)row * H_ + col] = acc[tm][tn][r4];
      }
}

// ---------------------------------------------------------------------------
extern "C" void kernel_launch(void* const* d_in, const int* in_sizes, int n_in,
                              void* d_out, int out_size, void* d_ws, size_t ws_size,
                              hipStream_t stream) {
  // setup_inputs order: key, query, value, W_Q, W_K, W_V (all fp32)
  const float* key   = (const float*)d_in[0];
  const float* query = (const float*)d_in[1];
  const float* value = (const float*)d_in[2];
  const float* WQ    = (const float*)d_in[3];
  const float* WK    = (const float*)d_in[4];
  const float* WV    = (const float*)d_in[5];
  float* out = (float*)d_out;

  char* w = (char*)d_ws;
  short* WtQ = (short*)(w + 0);                       // 3 x 256 KB
  short* WtK = (short*)(w + 262144);
  short* WtV = (short*)(w + 524288);
  size_t o = 786432;
  short* q  = (short*)(w + o); o += 4194304;          // (B,S,H) bf16
  short* k  = (short*)(w + o); o += 4194304;
  short* kT = (short*)(w + o); o += 4194304;          // (B,H,S) bf16
  short* vT = (short*)(w + o); o += 4194304;
  float* M  = (float*)(w + o); o += 8388608;          // (B,NC,128,128) f32

  wt_kernel   <<<dim3(32, 4, 3),       256, 0, stream>>>(WQ, WK, WV, WtQ, WtK, WtV);
  proj_kernel <<<dim3(256, 3),         256, 0, stream>>>(query, key, value,
                                                         WtQ, WtK, WtV, q, k, kT, vT);
  chunk_state <<<dim3(15, 4, B_),      256, 0, stream>>>(vT, kT, M);
  passC       <<<dim3(NC_, 4, B_),     256, 0, stream>>>(q, k, vT, M, out);
}

// Round 6
// 232.795 us; speedup vs baseline: 1.1899x; 1.1899x over previous
//
#include <hip/hip_runtime.h>
#include <cstdint>

#define B_  8
#define S_  2048
#define E_  1024
#define H_  128
#define NC_ 16          // chunks per sequence (S_/128)

typedef __attribute__((ext_vector_type(8))) short bf16x8;
typedef __attribute__((ext_vector_type(4))) float f32x4;

__device__ __forceinline__ short f2bf(float f){
  uint32_t u = __builtin_bit_cast(uint32_t, f);
  u = (u + 0x7fffu + ((u >> 16) & 1u)) >> 16;   // RNE
  return (short)u;
}
__device__ __forceinline__ float bf2f(short s){
  uint32_t u = ((uint32_t)(uint16_t)s) << 16;
  return __builtin_bit_cast(float, u);
}

// ---------------------------------------------------------------------------
// Kernel 1: W (E,H) f32 -> Wt (H,E) bf16, LDS-tiled transpose
// ---------------------------------------------------------------------------
__global__ __launch_bounds__(256) void wt_kernel(
    const float* __restrict__ WQ, const float* __restrict__ WK,
    const float* __restrict__ WV,
    short* __restrict__ WtQ, short* __restrict__ WtK, short* __restrict__ WtV)
{
  int which = blockIdx.z;
  const float* W = which == 0 ? WQ : which == 1 ? WK : WV;
  short* Wt      = which == 0 ? WtQ : which == 1 ? WtK : WtV;
  int k0 = blockIdx.x * 32, n0 = blockIdx.y * 32;
  __shared__ float t[32][33];
  int tx = threadIdx.x & 31, ty = threadIdx.x >> 5;
  #pragma unroll
  for (int i = 0; i < 4; i++)
    t[ty + i * 8][tx] = W[(size_t)(k0 + ty + i * 8) * H_ + n0 + tx];
  __syncthreads();
  #pragma unroll
  for (int i = 0; i < 4; i++)
    Wt[(size_t)(n0 + ty + i * 8) * E_ + k0 + tx] = f2bf(t[tx][ty + i * 8]);
}

// ---------------------------------------------------------------------------
// Kernel 2: projections — r0 VERBATIM (verified local optimum, 82.5 µs).
// r1 (64-k dbuf), r2 (no-LDS direct B), r3 (A via LDS), all regressed.
// ---------------------------------------------------------------------------
__global__ __launch_bounds__(256) void proj_kernel(
    const float* __restrict__ Xq, const float* __restrict__ Xk,
    const float* __restrict__ Xv,
    const short* __restrict__ Wtq, const short* __restrict__ Wtk,
    const short* __restrict__ Wtv,
    short* __restrict__ q, short* __restrict__ k,
    short* __restrict__ kT, short* __restrict__ vT)
{
  int which = blockIdx.y;
  const float* X  = which == 0 ? Xq  : which == 1 ? Xk  : Xv;
  const short* Wt = which == 0 ? Wtq : which == 1 ? Wtk : Wtv;

  int tid = threadIdx.x, lane = tid & 63, wave = tid >> 6;
  int lr = lane & 15, lq = lane >> 4;
  int rowbase = blockIdx.x * 64 + wave * 16;   // wave's 16 rows

  __shared__ short Bs[128 * 136];              // padded stride 136 (34.8 KB)

  const float* xr = X + (size_t)(rowbase + lr) * E_ + lq * 8;

  f32x4 acc[8];
  #pragma unroll
  for (int tn = 0; tn < 8; tn++) acc[tn] = (f32x4){0.f, 0.f, 0.f, 0.f};

  for (int kc = 0; kc < 8; kc++){              // 128-k chunks
    if (kc) __syncthreads();                   // prev chunk's reads done
    // volley: stage B chunk, 128 rows x 128 shorts; 8 x 16B per thread
    #pragma unroll
    for (int v = 0; v < 8; v++){
      int c = v * 256 + tid;
      int n = c >> 4, off = (c & 15) * 8;
      *(bf16x8*)(&Bs[n * 136 + off]) =
          *(const bf16x8*)(Wt + (size_t)n * E_ + kc * 128 + off);
    }
    // A for the whole chunk: 8 x f32x4 in flight
    f32x4 ar[8];
    #pragma unroll
    for (int s = 0; s < 4; s++){
      ar[2 * s]     = *(const f32x4*)(xr + kc * 128 + s * 32);
      ar[2 * s + 1] = *(const f32x4*)(xr + kc * 128 + s * 32 + 4);
    }
    __syncthreads();                           // single drain per chunk
    #pragma unroll
    for (int s = 0; s < 4; s++){
      bf16x8 a;
      #pragma unroll
      for (int j = 0; j < 4; j++){
        a[j] = f2bf(ar[2 * s][j]); a[4 + j] = f2bf(ar[2 * s + 1][j]);
      }
      #pragma unroll
      for (int tn = 0; tn < 8; tn++){
        bf16x8 bfr = *(const bf16x8*)(&Bs[(tn * 16 + lr) * 136 + s * 32 + lq * 8]);
        acc[tn] = __builtin_amdgcn_mfma_f32_16x16x32_bf16(a, bfr, acc[tn], 0, 0, 0);
      }
    }
  }

  // ---- epilogue: C/D layout col=lane&15, row=(lane>>4)*4+reg ----
  if (which <= 1){
    short* P = which == 0 ? q : k;
    #pragma unroll
    for (int tn = 0; tn < 8; tn++)
      #pragma unroll
      for (int r4 = 0; r4 < 4; r4++)
        P[(size_t)(rowbase + lq * 4 + r4) * H_ + tn * 16 + lr] = f2bf(acc[tn][r4]);
  }
  if (which >= 1){
    short* T = which == 1 ? kT : vT;
    int b = rowbase >> 11, srow = rowbase & 2047;
    #pragma unroll
    for (int tn = 0; tn < 8; tn++){
      union { short sh[4]; uint2 u; } pk;
      #pragma unroll
      for (int r4 = 0; r4 < 4; r4++) pk.sh[r4] = f2bf(acc[tn][r4]);
      *(uint2*)(T + ((size_t)b * H_ + tn * 16 + lr) * S_ + srow + lq * 4) = pk.u;
    }
  }
}

// ---------------------------------------------------------------------------
// Kernel 3: per-chunk state M_j[h'][h] = sum_t V[t][h'] K[t][h].
// Col QUARTERS (32 h each); grid (15,4,B) — j=15 unused by exclusive prefix.
// ---------------------------------------------------------------------------
__global__ __launch_bounds__(256) void chunk_state(
    const short* __restrict__ vT, const short* __restrict__ kT,
    float* __restrict__ M)
{
  int j = blockIdx.x, qtr = blockIdx.y, b = blockIdx.z;
  int tid = threadIdx.x, lane = tid & 63, wave = tid >> 6;
  int wrow = wave * 32;
  int lr = lane & 15, lq = lane >> 4;

  __shared__ short As[128 * 136];   // vT rows (h' x t), 34.8 KB
  __shared__ short Bs[32 * 136];    // kT quarter rows (h x t), 8.7 KB

  const short* vtb = vT + (size_t)b * H_ * S_ + j * 128;
  const short* ktb = kT + (size_t)b * H_ * S_ + (size_t)qtr * 32 * S_ + j * 128;

  #pragma unroll
  for (int v = 0; v < 8; v++){
    int c = v * 256 + tid;
    int r = c >> 4, off = (c & 15) * 8;
    *(bf16x8*)(&As[r * 136 + off]) = *(const bf16x8*)(vtb + (size_t)r * S_ + off);
  }
  #pragma unroll
  for (int v = 0; v < 2; v++){
    int c = v * 256 + tid;
    int r = c >> 4, off = (c & 15) * 8;
    *(bf16x8*)(&Bs[r * 136 + off]) = *(const bf16x8*)(ktb + (size_t)r * S_ + off);
  }
  __syncthreads();

  f32x4 acc[2][2];
  #pragma unroll
  for (int a = 0; a < 2; a++)
    #pragma unroll
    for (int c = 0; c < 2; c++) acc[a][c] = (f32x4){0.f, 0.f, 0.f, 0.f};

  #pragma unroll
  for (int s = 0; s < 4; s++){
    int t0 = s * 32;
    bf16x8 af[2], bf[2];
    #pragma unroll
    for (int tm = 0; tm < 2; tm++)
      af[tm] = *(const bf16x8*)(&As[(wrow + tm * 16 + lr) * 136 + t0 + lq * 8]);
    #pragma unroll
    for (int tn = 0; tn < 2; tn++)
      bf[tn] = *(const bf16x8*)(&Bs[(tn * 16 + lr) * 136 + t0 + lq * 8]);
    #pragma unroll
    for (int tm = 0; tm < 2; tm++)
      #pragma unroll
      for (int tn = 0; tn < 2; tn++)
        acc[tm][tn] = __builtin_amdgcn_mfma_f32_16x16x32_bf16(
            af[tm], bf[tn], acc[tm][tn], 0, 0, 0);
  }

  float* mb = M + (size_t)(b * NC_ + j) * 16384;
  #pragma unroll
  for (int tm = 0; tm < 2; tm++)
    #pragma unroll
    for (int tn = 0; tn < 2; tn++)
      #pragma unroll
      for (int r4 = 0; r4 < 4; r4++){
        int row = wrow + tm * 16 + lq * 4 + r4;
        int col = qtr * 32 + tn * 16 + lr;
        mb[row * 128 + col] = acc[tm][tn][r4];
      }
}

// ---------------------------------------------------------------------------
// Kernel 4: exclusive prefix of M over chunks -> bf16 hi + residual lo.
// float2/thread, grid (32,B) = 256 blocks. Loads only M_0..M_14 (M_15
// is never produced nor needed by the exclusive prefix).
// ---------------------------------------------------------------------------
__global__ __launch_bounds__(256) void prefix_state(
    const float* __restrict__ M, short* __restrict__ Shi, short* __restrict__ Slo)
{
  int b = blockIdx.y;
  int idx = (blockIdx.x * 256 + threadIdx.x) * 2;
  float2 mv[NC_ - 1];
  #pragma unroll
  for (int j = 0; j < NC_ - 1; j++)
    mv[j] = *(const float2*)(M + (size_t)(b * NC_ + j) * 16384 + idx);

  float r0 = 0.f, r1 = 0.f;
  #pragma unroll
  for (int j = 0; j < NC_; j++){
    size_t o = (size_t)(b * NC_ + j) * 16384 + idx;
    short h0 = f2bf(r0), h1 = f2bf(r1);
    short l0 = f2bf(r0 - bf2f(h0)), l1 = f2bf(r1 - bf2f(h1));
    union { short s[2]; uint32_t u; } ph, pl;
    ph.s[0] = h0; ph.s[1] = h1;
    pl.s[0] = l0; pl.s[1] = l1;
    *(uint32_t*)(Shi + o) = ph.u;
    *(uint32_t*)(Slo + o) = pl.u;
    if (j < NC_ - 1){ r0 += mv[j].x; r1 += mv[j].y; }
  }
}

// ---------------------------------------------------------------------------
// Kernel 5: per (b, chunk i, row-QUARTER): 32 rows of
//   O = (Q_i K_i^T . tril) V_i + Q_i (State_hi + State_lo)
// r3 verbatim (part of the best-measured 140 µs tail). All global tile
// loads issued at kernel entry into regs (T14). 4 barriers.
// ---------------------------------------------------------------------------
__global__ __launch_bounds__(256) void passC(
    const short* __restrict__ qb, const short* __restrict__ kb,
    const short* __restrict__ vT, const short* __restrict__ Shi,
    const short* __restrict__ Slo, float* __restrict__ out)
{
  int i = blockIdx.x, qtr = blockIdx.y, b = blockIdx.z;
  int roff = qtr * 32;
  int tid = threadIdx.x, lane = tid & 63, wave = tid >> 6;
  int wcol = wave * 32;
  int lr = lane & 15, lq = lane >> 4;

  __shared__ short Ss[32 * 136];    // masked scores (8.7 KB)
  __shared__ short Bt0[128 * 136];  // K, then Shi  (34.8 KB)
  __shared__ short Bt1[128 * 136];  // V, then Slo  (34.8 KB)

  const short* qbase = qb + ((size_t)b * S_ + i * 128 + roff) * H_;
  const short* kbase = kb + ((size_t)b * S_ + i * 128) * H_;
  const short* vtb   = vT + (size_t)b * H_ * S_ + i * 128;
  const short* shib  = Shi + (size_t)(b * NC_ + i) * 16384;
  const short* slob  = Slo + (size_t)(b * NC_ + i) * 16384;

  // ---- issue ALL global loads up front: 40 x 16B per lane in flight ----
  bf16x8 kst[8], vst[8], hst[8], lst[8];
  #pragma unroll
  for (int v = 0; v < 8; v++){
    int c = v * 256 + tid;
    int r = c >> 4, off = (c & 15) * 8;
    kst[v] = *(const bf16x8*)(kbase + (size_t)r * H_ + off);
    vst[v] = *(const bf16x8*)(vtb  + (size_t)r * S_ + off);
    hst[v] = *(const bf16x8*)(shib + (size_t)r * 128 + off);
    lst[v] = *(const bf16x8*)(slob + (size_t)r * 128 + off);
  }
  bf16x8 aq[2][4];   // Q rows tm*16+lr (32 rows of this quarter)
  #pragma unroll
  for (int tm = 0; tm < 2; tm++)
    #pragma unroll
    for (int hs = 0; hs < 4; hs++)
      aq[tm][hs] = *(const bf16x8*)(
          qbase + (size_t)(tm * 16 + lr) * H_ + hs * 32 + lq * 8);

  // K -> Bt0
  #pragma unroll
  for (int v = 0; v < 8; v++){
    int c = v * 256 + tid;
    int r = c >> 4, off = (c & 15) * 8;
    *(bf16x8*)(&Bt0[r * 136 + off]) = kst[v];
  }
  __syncthreads();                           // barrier 1

  f32x4 accS[2][2];
  #pragma unroll
  for (int a = 0; a < 2; a++)
    #pragma unroll
    for (int c = 0; c < 2; c++) accS[a][c] = (f32x4){0.f, 0.f, 0.f, 0.f};

  // ---- phase 1: S = Q K^T, wave's t-slice = wcol..wcol+31 ----
  #pragma unroll
  for (int hs = 0; hs < 4; hs++){
    bf16x8 bf[2];
    #pragma unroll
    for (int tn = 0; tn < 2; tn++)
      bf[tn] = *(const bf16x8*)(&Bt0[(wcol + tn * 16 + lr) * 136 + hs * 32 + lq * 8]);
    #pragma unroll
    for (int tm = 0; tm < 2; tm++)
      #pragma unroll
      for (int tn = 0; tn < 2; tn++)
        accS[tm][tn] = __builtin_amdgcn_mfma_f32_16x16x32_bf16(
            aq[tm][hs], bf[tn], accS[tm][tn], 0, 0, 0);
  }

  // ---- phase 2: mask + bf16 -> Ss; land V -> Bt1 ----
  #pragma unroll
  for (int tm = 0; tm < 2; tm++)
    #pragma unroll
    for (int tn = 0; tn < 2; tn++)
      #pragma unroll
      for (int r4 = 0; r4 < 4; r4++){
        int row = tm * 16 + lq * 4 + r4;            // local row 0..31
        int col = wcol + tn * 16 + lr;              // t index 0..127
        float vv = (col <= roff + row) ? accS[tm][tn][r4] : 0.f;
        Ss[row * 136 + col] = f2bf(vv);
      }
  #pragma unroll
  for (int v = 0; v < 8; v++){
    int c = v * 256 + tid;
    int r = c >> 4, off = (c & 15) * 8;
    *(bf16x8*)(&Bt1[r * 136 + off]) = vst[v];
  }
  f32x4 acc[2][2];
  #pragma unroll
  for (int a = 0; a < 2; a++)
    #pragma unroll
    for (int c = 0; c < 2; c++) acc[a][c] = (f32x4){0.f, 0.f, 0.f, 0.f};
  __syncthreads();                           // barrier 2

  // ---- phase 3a: O += S V, wave's h'-slice = wcol; land Shi -> Bt0 ----
  #pragma unroll
  for (int s = 0; s < 4; s++){
    int t0 = s * 32;
    bf16x8 af[2], bf[2];
    #pragma unroll
    for (int tm = 0; tm < 2; tm++)
      af[tm] = *(const bf16x8*)(&Ss[(tm * 16 + lr) * 136 + t0 + lq * 8]);
    #pragma unroll
    for (int tn = 0; tn < 2; tn++)
      bf[tn] = *(const bf16x8*)(&Bt1[(wcol + tn * 16 + lr) * 136 + t0 + lq * 8]);
    #pragma unroll
    for (int tm = 0; tm < 2; tm++)
      #pragma unroll
      for (int tn = 0; tn < 2; tn++)
        acc[tm][tn] = __builtin_amdgcn_mfma_f32_16x16x32_bf16(
            af[tm], bf[tn], acc[tm][tn], 0, 0, 0);
  }
  #pragma unroll
  for (int v = 0; v < 8; v++){
    int c = v * 256 + tid;
    int r = c >> 4, off = (c & 15) * 8;
    *(bf16x8*)(&Bt0[r * 136 + off]) = hst[v];
  }
  __syncthreads();                           // barrier 3

  // ---- phase 3b-hi: O += Q * State_hi (Bt0); land Slo -> Bt1 ----
  #pragma unroll
  for (int hs = 0; hs < 4; hs++){
    bf16x8 bf[2];
    #pragma unroll
    for (int tn = 0; tn < 2; tn++)
      bf[tn] = *(const bf16x8*)(&Bt0[(wcol + tn * 16 + lr) * 136 + hs * 32 + lq * 8]);
    #pragma unroll
    for (int tm = 0; tm < 2; tm++)
      #pragma unroll
      for (int tn = 0; tn < 2; tn++)
        acc[tm][tn] = __builtin_amdgcn_mfma_f32_16x16x32_bf16(
            aq[tm][hs], bf[tn], acc[tm][tn], 0, 0, 0);
  }
  #pragma unroll
  for (int v = 0; v < 8; v++){
    int c = v * 256 + tid;
    int r = c >> 4, off = (c & 15) * 8;
    *(bf16x8*)(&Bt1[r * 136 + off]) = lst[v];
  }
  __syncthreads();                           // barrier 4

  // ---- phase 3b-lo: O += Q * State_lo (Bt1) ----
  #pragma unroll
  for (int hs = 0; hs < 4; hs++){
    bf16x8 bf[2];
    #pragma unroll
    for (int tn = 0; tn < 2; tn++)
      bf[tn] = *(const bf16x8*)(&Bt1[(wcol + tn * 16 + lr) * 136 + hs * 32 + lq * 8]);
    #pragma unroll
    for (int tm = 0; tm < 2; tm++)
      #pragma unroll
      for (int tn = 0; tn < 2; tn++)
        acc[tm][tn] = __builtin_amdgcn_mfma_f32_16x16x32_bf16(
            aq[tm][hs], bf[tn], acc[tm][tn], 0, 0, 0);
  }

  // ---- epilogue ----
  float* ob = out + ((size_t)b * S_ + i * 128 + roff) * H_;
  #pragma unroll
  for (int tm = 0; tm < 2; tm++)
    #pragma unroll
    for (int tn = 0; tn < 2; tn++)
      #pragma unroll
      for (int r4 = 0; r4 < 4; r4++){
        int row = tm * 16 + lq * 4 + r4;
        int col = wcol + tn * 16 + lr;
        ob[(size_t)row * H_ + col] = acc[tm][tn][r4];
      }
}

// ---------------------------------------------------------------------------
extern "C" void kernel_launch(void* const* d_in, const int* in_sizes, int n_in,
                              void* d_out, int out_size, void* d_ws, size_t ws_size,
                              hipStream_t stream) {
  // setup_inputs order: key, query, value, W_Q, W_K, W_V (all fp32)
  const float* key   = (const float*)d_in[0];
  const float* query = (const float*)d_in[1];
  const float* value = (const float*)d_in[2];
  const float* WQ    = (const float*)d_in[3];
  const float* WK    = (const float*)d_in[4];
  const float* WV    = (const float*)d_in[5];
  float* out = (float*)d_out;

  char* w = (char*)d_ws;
  short* WtQ = (short*)(w + 0);                       // 3 x 256 KB
  short* WtK = (short*)(w + 262144);
  short* WtV = (short*)(w + 524288);
  size_t o = 786432;
  short* q  = (short*)(w + o); o += 4194304;          // (B,S,H) bf16
  short* k  = (short*)(w + o); o += 4194304;
  short* kT = (short*)(w + o); o += 4194304;          // (B,H,S) bf16
  short* vT = (short*)(w + o); o += 4194304;
  float* M  = (float*)(w + o); o += 8388608;          // (B,NC,128,128) f32
  short* Shi= (short*)(w + o); o += 4194304;          // exclusive prefix, bf16 hi
  short* Slo= (short*)(w + o); o += 4194304;          // bf16 residual

  wt_kernel   <<<dim3(32, 4, 3),       256, 0, stream>>>(WQ, WK, WV, WtQ, WtK, WtV);
  proj_kernel <<<dim3(256, 3),         256, 0, stream>>>(query, key, value,
                                                         WtQ, WtK, WtV, q, k, kT, vT);
  chunk_state <<<dim3(15, 4, B_),      256, 0, stream>>>(vT, kT, M);
  prefix_state<<<dim3(32, B_),         256, 0, stream>>>(M, Shi, Slo);
  passC       <<<dim3(NC_, 4, B_),     256, 0, stream>>>(q, k, vT, Shi, Slo, out);
}